// Round 7
// baseline (83.964 us; speedup 1.0000x reference)
//
#include <hip/hip_runtime.h>

// Tropical (max-plus) linear layer:
//   out[b, j] = max_k (x[b,k] + w[j,k]) + bias[j]   if any product > -1e38
//             = -1e38                                otherwise
// x: [4096, 256] f32, w: [256, 256] f32, bias: [256] f32, out: [4096, 256] f32
//
// R10 = R9 body UNCHANGED + the tropical kernel launched TWICE (idempotent:
// identical inputs -> identical out; second launch rewrites the same bytes).
// This is a deliberate measurement round. Ledger so far: 4 memory-path
// structures, a coalesced-w prologue fix, and a -33% VALU cut ALL produced
// zero dur_us delta (~72us = fill ~40.6 + residual ~31.5). The duplicate
// launch separates the two surviving models:
//   (A) kernel really ~31us  -> dur_us ~100-105
//   (B) kernel ~5us + ~26us harness floor -> dur_us ~75-78 -> declare roofline
//
// Body provenance: R7 structure (transpose_w pre-kernel, coalesced wT loads,
// x via scalar-path double-buffer, LDS only for 8-way k-combine) + R8/R9
// packed adds (v_pk_add_f32 with SGPR x-operand).

#define TZERO -1e38f

constexpr int K    = 256;
constexpr int N    = 256;
constexpr int ROWS = 16;    // rows per block
constexpr int COLS = 128;   // cols per block (2 per lane)
constexpr int NT   = 512;   // 8 waves = 8 k-segments
constexpr int KSEG = 32;    // k-extent per wave

typedef float f32x2 __attribute__((ext_vector_type(2)));

// ---------------------------------------------------------------- transpose
__global__ __launch_bounds__(256)
void transpose_w(const float* __restrict__ w, float* __restrict__ wT)
{
    __shared__ float ls[64][65];          // +1 pad: conflict-free columns
    const int bi = blockIdx.x * 64;       // row block in w  (cols of wT)
    const int bj = blockIdx.y * 64;       // col block in w  (rows of wT)
    const int t  = threadIdx.x;
    const int lr = t >> 4;                // 0..15
    const int lc = (t & 15) * 4;          // 0,4,...,60

#pragma unroll
    for (int i = 0; i < 4; ++i) {         // coalesced read of w rows
        const int r = lr + i * 16;
        const float4 v =
            *reinterpret_cast<const float4*>(w + (size_t)(bi + r) * K + bj + lc);
        ls[r][lc + 0] = v.x; ls[r][lc + 1] = v.y;
        ls[r][lc + 2] = v.z; ls[r][lc + 3] = v.w;
    }
    __syncthreads();
#pragma unroll
    for (int i = 0; i < 4; ++i) {         // coalesced write of wT rows
        const int kk = lr + i * 16;       // k index within tile
        float4 v;
        v.x = ls[lc + 0][kk]; v.y = ls[lc + 1][kk];
        v.z = ls[lc + 2][kk]; v.w = ls[lc + 3][kk];
        *reinterpret_cast<float4*>(wT + (size_t)(bj + kk) * N + bi + lc) = v;
    }
}

// ---------------------------------------------------------------- main
// packed add: d = {xs.x + wv.x, xs.y + wv.y}; xs is wave-uniform (SGPR pair)
__device__ __forceinline__ f32x2 pk_add_sv(f32x2 xs, f32x2 wv)
{
    f32x2 r;
    asm("v_pk_add_f32 %0, %1, %2" : "=v"(r) : "s"(xs), "v"(wv));
    return r;
}

__device__ __forceinline__ void row_compute(
    const float4 (&buf)[8], const f32x2 (&wA)[16], const f32x2 (&wB)[16],
    float& a0, float& a1)
{
    float p0 = -__builtin_inff(), p1 = -__builtin_inff();
    float q0 = -__builtin_inff(), q1 = -__builtin_inff();
#pragma unroll
    for (int i = 0; i < 8; ++i) {
        const f32x2 xlo = {buf[i].x, buf[i].y};   // s[4i:4i+1], even-aligned
        const f32x2 xhi = {buf[i].z, buf[i].w};   // s[4i+2:4i+3], even-aligned
        const f32x2 r0 = pk_add_sv(xlo, wA[2 * i + 0]);
        const f32x2 r1 = pk_add_sv(xhi, wA[2 * i + 1]);
        p0 = fmaxf(fmaxf(p0, r0.x), r0.y);        // v_max3_f32
        p1 = fmaxf(fmaxf(p1, r1.x), r1.y);        // v_max3_f32
        const f32x2 r2 = pk_add_sv(xlo, wB[2 * i + 0]);
        const f32x2 r3 = pk_add_sv(xhi, wB[2 * i + 1]);
        q0 = fmaxf(fmaxf(q0, r2.x), r2.y);
        q1 = fmaxf(fmaxf(q1, r3.x), r3.y);
    }
    a0 = fmaxf(p0, p1);
    a1 = fmaxf(q0, q1);
}

__global__ __launch_bounds__(NT, 2)
void tropical_kernel(const float* __restrict__ x, const float* __restrict__ wT,
                     const float* __restrict__ bias, float* __restrict__ out)
{
    __shared__ float part[8][ROWS][COLS];   // 64 KB, only LDS use

    const int t    = threadIdx.x;
    const int lane = t & 63;
    const int ws   = __builtin_amdgcn_readfirstlane(t >> 6);  // k-segment id
    const int row0 = blockIdx.x * ROWS;
    const int col0 = blockIdx.y * COLS;

    // ---- w fragments from wT: coalesced (lane = col), packed as k-pairs
    //      so each f32x2 lands in an even-aligned VGPR pair for v_pk_add_f32
    const int k0 = ws * KSEG;
    f32x2 wA[16], wB[16];
    {
        const float* wp = wT + (size_t)k0 * N + col0 + lane;
#pragma unroll
        for (int i = 0; i < 16; ++i) {
            wA[i] = f32x2{wp[(size_t)(2 * i) * N],      wp[(size_t)(2 * i + 1) * N]};
            wB[i] = f32x2{wp[(size_t)(2 * i) * N + 64], wp[(size_t)(2 * i + 1) * N + 64]};
        }
    }

    // ---- x through the scalar path: 8 float4 = 32 SGPRs per row,
    //      2-row double-buffer with NAMED static buffers (no runtime index)
    const float* xp = x + (size_t)row0 * K + k0;   // wave-uniform base

    float4 bA[8], bB[8];
#pragma unroll
    for (int i = 0; i < 8; ++i)
        bA[i] = *reinterpret_cast<const float4*>(xp + 4 * i);   // row 0

    float a0, a1;
#pragma unroll 1
    for (int r = 0; r < ROWS; r += 2) {
        // prefetch row r+1 while computing row r
#pragma unroll
        for (int i = 0; i < 8; ++i)
            bB[i] = *reinterpret_cast<const float4*>(xp + (r + 1) * K + 4 * i);

        row_compute(bA, wA, wB, a0, a1);
        part[ws][r][lane]      = a0;
        part[ws][r][64 + lane] = a1;

        if (r + 2 < ROWS) {
#pragma unroll
            for (int i = 0; i < 8; ++i)
                bA[i] = *reinterpret_cast<const float4*>(xp + (r + 2) * K + 4 * i);
        }

        row_compute(bB, wA, wB, a0, a1);
        part[ws][r + 1][lane]      = a0;
        part[ws][r + 1][64 + lane] = a1;
    }

    __syncthreads();

    // ---- epilogue: 8-way k-segment combine, bias, guard, coalesced store
    {
        const int c  = t & 127;
        const int rb = t >> 7;             // 0..3
        const float bj = bias[col0 + c];
#pragma unroll
        for (int j = 0; j < 4; ++j) {
            const int r = rb + 4 * j;
            float v = part[0][r][c];
#pragma unroll
            for (int s = 1; s < 8; ++s) v = fmaxf(v, part[s][r][c]);
            out[(size_t)(row0 + r) * N + col0 + c] = (v > TZERO) ? v + bj : TZERO;
        }
    }
}

extern "C" void kernel_launch(void* const* d_in, const int* in_sizes, int n_in,
                              void* d_out, int out_size, void* d_ws, size_t ws_size,
                              hipStream_t stream) {
    const float* x  = (const float*)d_in[0];
    const float* w  = (const float*)d_in[1];
    const float* b  = (const float*)d_in[2];
    float* out      = (float*)d_out;
    float* wT       = (float*)d_ws;     // 256 KB scratch for transposed w

    dim3 tg(4, 4);                       // 16 tiles of 64x64
    transpose_w<<<tg, 256, 0, stream>>>(w, wT);

    dim3 grid(4096 / ROWS, N / COLS);    // (256, 2) = 512 blocks, 8 waves each
    // MEASUREMENT: launch the (idempotent) main kernel TWICE. The dur_us
    // delta vs the single-launch run (72.16us) is the kernel's true cost:
    //   ~+31us -> kernel-bound residual is real, keep optimizing
    //   ~+5us  -> harness floor, declare roofline next round
    tropical_kernel<<<grid, NT, 0, stream>>>(x, wT, b, out);
    tropical_kernel<<<grid, NT, 0, stream>>>(x, wT, b, out);
}

// Round 8
// 71.072 us; speedup vs baseline: 1.1814x; 1.1814x over previous
//
#include <hip/hip_runtime.h>

// Tropical (max-plus) linear layer:
//   out[b, j] = max_k (x[b,k] + w[j,k]) + bias[j]   if any product > -1e38
//             = -1e38                                otherwise
// x: [4096, 256] f32, w: [256, 256] f32, bias: [256] f32, out: [4096, 256] f32
//
// R11 = R9 body, SINGLE dispatch (transpose_w removed).
//  - R10 duplicate-launch measurement: marginal kernel cost = 11.8us.
//    Iteration decomposition: fill 40.6 + kernel 11.8 + transpose/gap ~2-4 +
//    fixed overhead ~17. All prior "kernel" optimizations were fighting the
//    fixed overhead, not the kernel.
//  - R7==R3==R0 proved coalesced-w (wT) == scatter-w -> the transpose
//    pre-kernel is pure dispatch overhead. Removed: w loaded directly,
//    per-lane contiguous k (8 x float4 per col, lanes stride 1KB).
//  - Kernel body unchanged from R9 (best measured, passed, absmax 0):
//    8 waves = 8 k-segments of 32; w in VGPRs (2 cols x 32k); x via scalar
//    path 2-row double-buffer; v_pk_add_f32 with SGPR x-operand; LDS only
//    for the 8-way k-segment combine (64KB part).
//  - Pre-committed: if dur_us doesn't drop below ~71.5, kernel is at its
//    ~11.8us latency/clock floor (VALU-issue floor 3.4us unreachable;
//    R7->R9 -33% VALU was null) and next round declares ROOFLINE.

#define TZERO -1e38f

constexpr int K    = 256;
constexpr int N    = 256;
constexpr int ROWS = 16;    // rows per block
constexpr int COLS = 128;   // cols per block (2 per lane)
constexpr int NT   = 512;   // 8 waves = 8 k-segments
constexpr int KSEG = 32;    // k-extent per wave

typedef float f32x2 __attribute__((ext_vector_type(2)));

// packed add: d = {xs.x + wv.x, xs.y + wv.y}; xs is wave-uniform (SGPR pair)
__device__ __forceinline__ f32x2 pk_add_sv(f32x2 xs, f32x2 wv)
{
    f32x2 r;
    asm("v_pk_add_f32 %0, %1, %2" : "=v"(r) : "s"(xs), "v"(wv));
    return r;
}

__device__ __forceinline__ void row_compute(
    const float4 (&buf)[8], const float4 (&wA)[8], const float4 (&wB)[8],
    float& a0, float& a1)
{
    float p0 = -__builtin_inff(), p1 = -__builtin_inff();
    float q0 = -__builtin_inff(), q1 = -__builtin_inff();
#pragma unroll
    for (int i = 0; i < 8; ++i) {
        const f32x2 xlo = {buf[i].x, buf[i].y};   // SGPR pair, even-aligned
        const f32x2 xhi = {buf[i].z, buf[i].w};   // SGPR pair, even-aligned
        const f32x2 wa0 = {wA[i].x, wA[i].y};     // VGPR pairs (quad subpairs)
        const f32x2 wa1 = {wA[i].z, wA[i].w};
        const f32x2 wb0 = {wB[i].x, wB[i].y};
        const f32x2 wb1 = {wB[i].z, wB[i].w};
        const f32x2 r0 = pk_add_sv(xlo, wa0);
        const f32x2 r1 = pk_add_sv(xhi, wa1);
        p0 = fmaxf(fmaxf(p0, r0.x), r0.y);        // v_max3_f32
        p1 = fmaxf(fmaxf(p1, r1.x), r1.y);        // v_max3_f32
        const f32x2 r2 = pk_add_sv(xlo, wb0);
        const f32x2 r3 = pk_add_sv(xhi, wb1);
        q0 = fmaxf(fmaxf(q0, r2.x), r2.y);
        q1 = fmaxf(fmaxf(q1, r3.x), r3.y);
    }
    a0 = fmaxf(p0, p1);
    a1 = fmaxf(q0, q1);
}

__global__ __launch_bounds__(NT, 2)
void tropical_kernel(const float* __restrict__ x, const float* __restrict__ w,
                     const float* __restrict__ bias, float* __restrict__ out)
{
    __shared__ float part[8][ROWS][COLS];   // 64 KB, only LDS use

    const int t    = threadIdx.x;
    const int lane = t & 63;
    const int ws   = __builtin_amdgcn_readfirstlane(t >> 6);  // k-segment id
    const int row0 = blockIdx.x * ROWS;
    const int col0 = blockIdx.y * COLS;

    // ---- w fragments DIRECT from w: per lane the 32 k-values are contiguous
    //      (w[col, k0..k0+31] = 128B) -> 8 x float4 per col, 16 loads total.
    //      Lanes stride 1KB (scatter) -- measured equal to coalesced wT (R7).
    const int k0 = ws * KSEG;
    const float* wp0 = w + (size_t)(col0 + lane) * K + k0;   // col A
    const float* wp1 = wp0 + (size_t)64 * K;                  // col B (+64)
    float4 wA[8], wB[8];
#pragma unroll
    for (int i = 0; i < 8; ++i) {
        wA[i] = *reinterpret_cast<const float4*>(wp0 + 4 * i);
        wB[i] = *reinterpret_cast<const float4*>(wp1 + 4 * i);
    }

    // ---- x through the scalar path: 8 float4 = 32 SGPRs per row,
    //      2-row double-buffer with NAMED static buffers (no runtime index)
    const float* xp = x + (size_t)row0 * K + k0;   // wave-uniform base

    float4 bA[8], bB[8];
#pragma unroll
    for (int i = 0; i < 8; ++i)
        bA[i] = *reinterpret_cast<const float4*>(xp + 4 * i);   // row 0

    float a0, a1;
#pragma unroll 1
    for (int r = 0; r < ROWS; r += 2) {
        // prefetch row r+1 while computing row r
#pragma unroll
        for (int i = 0; i < 8; ++i)
            bB[i] = *reinterpret_cast<const float4*>(xp + (r + 1) * K + 4 * i);

        row_compute(bA, wA, wB, a0, a1);
        part[ws][r][lane]      = a0;
        part[ws][r][64 + lane] = a1;

        if (r + 2 < ROWS) {
#pragma unroll
            for (int i = 0; i < 8; ++i)
                bA[i] = *reinterpret_cast<const float4*>(xp + (r + 2) * K + 4 * i);
        }

        row_compute(bB, wA, wB, a0, a1);
        part[ws][r + 1][lane]      = a0;
        part[ws][r + 1][64 + lane] = a1;
    }

    __syncthreads();

    // ---- epilogue: 8-way k-segment combine, bias, guard, coalesced store
    {
        const int c  = t & 127;
        const int rb = t >> 7;             // 0..3
        const float bj = bias[col0 + c];
#pragma unroll
        for (int j = 0; j < 4; ++j) {
            const int r = rb + 4 * j;
            float v = part[0][r][c];
#pragma unroll
            for (int s = 1; s < 8; ++s) v = fmaxf(v, part[s][r][c]);
            out[(size_t)(row0 + r) * N + col0 + c] = (v > TZERO) ? v + bj : TZERO;
        }
    }
}

extern "C" void kernel_launch(void* const* d_in, const int* in_sizes, int n_in,
                              void* d_out, int out_size, void* d_ws, size_t ws_size,
                              hipStream_t stream) {
    const float* x  = (const float*)d_in[0];
    const float* w  = (const float*)d_in[1];
    const float* b  = (const float*)d_in[2];
    float* out      = (float*)d_out;

    dim3 grid(4096 / ROWS, N / COLS);    // (256, 2) = 512 blocks, 8 waves each
    tropical_kernel<<<grid, NT, 0, stream>>>(x, w, b, out);
}